// Round 12
// baseline (2194.908 us; speedup 1.0000x reference)
//
#include <hip/hip_runtime.h>
#include <stdint.h>

typedef _Float16 half8 __attribute__((ext_vector_type(8)));
typedef float f32x4 __attribute__((ext_vector_type(4)));

#define DDIM 256
#define KCODES 4096
#define BM 64
#define DELTA 0.02f
#define FLT_BIG 3.4e38f

#define GLOAD_LDS(gsrc, ldst)                                                        \
    __builtin_amdgcn_global_load_lds(                                                \
        (const __attribute__((address_space(1))) void*)(const void*)(gsrc),          \
        (__attribute__((address_space(3))) void*)(void*)(ldst), 16, 0, 0)

// ---------- codebook -> fragment-ordered hi/lo fp16 ----------
// cbp[g*1024 + k*128 + part*64 + l] (half8 units), lane l: code g*16+(l&15),
// dims k*32 + ((l>>4)&3)*8 .. +7   (part 0 = hi, 1 = lo)
__global__ void cvt_cb_kernel(const float* __restrict__ cb, half8* __restrict__ cbp) {
    int gid = blockIdx.x * 256 + threadIdx.x;    // 131072
    int l = gid & 63;
    int k = (gid >> 6) & 7;
    int g = gid >> 9;
    int code = g * 16 + (l & 15);
    int quad = (l >> 4) & 3;
    const float* s = cb + (size_t)code * DDIM + k * 32 + quad * 8;
    float4 f0 = ((const float4*)s)[0];
    float4 f1 = ((const float4*)s)[1];
    float ff[8] = {f0.x, f0.y, f0.z, f0.w, f1.x, f1.y, f1.z, f1.w};
    half8 hv, lv;
    #pragma unroll
    for (int j = 0; j < 8; ++j) {
        float v = ff[j];
        _Float16 h = (_Float16)v;
        hv[j] = h; lv[j] = (_Float16)(v - (float)h);
    }
    cbp[(size_t)(g * 8 + k) * 128 + l] = hv;
    cbp[(size_t)(g * 8 + k) * 128 + 64 + l] = lv;
}

__global__ void enorm_kernel(const float* __restrict__ cb, float* __restrict__ en, int K) {
    int gid = blockIdx.x * blockDim.x + threadIdx.x;
    int code = gid >> 6;
    int lane = threadIdx.x & 63;
    if (code >= K) return;
    const float4 v = *reinterpret_cast<const float4*>(&cb[(size_t)code * DDIM + lane * 4]);
    float s = v.x * v.x + v.y * v.y + v.z * v.z + v.w * v.w;
    #pragma unroll
    for (int off = 32; off > 0; off >>= 1) s += __shfl_xor(s, off, 64);
    if (lane == 0) en[code] = s;
}

// ---------------- main: A-stationary regs, barrier-free K-loop, B reg-dbuf prefetch ----------------
__global__ __launch_bounds__(512, 2)
void vq_mfma_kernel(const float* __restrict__ x, const half8* __restrict__ cbp,
                    const float* __restrict__ en, int* __restrict__ bidx,
                    int* __restrict__ list, int* __restrict__ counter) {
    __shared__ __align__(16) float xs[BM * DDIM];     // 64 KB staged x (chunk-swizzled)
    __shared__ float en_lds[KCODES];                  // 16 KB
    __shared__ float red_d[8][BM];
    __shared__ float red_d2[8][BM];
    __shared__ int   red_i[8][BM];

    const int tid = threadIdx.x;
    const int lane = tid & 63;
    const int w = tid >> 6;
    const int l15 = lane & 15, l4 = lane >> 4;
    const int brow = blockIdx.x * BM;

    ((float4*)en_lds)[tid] = ((const float4*)en)[tid];
    ((float4*)en_lds)[tid + 512] = ((const float4*)en)[tid + 512];

    // ---- stage x rows (fp32) into LDS, chunk-XOR swizzled, coalesced ----
    #pragma unroll
    for (int i = 0; i < 8; ++i) {
        const int row = i * 8 + w;                    // row & 7 == w (wave-uniform)
        const float* src = x + (size_t)(brow + row) * DDIM + ((lane ^ w) << 2);
        GLOAD_LDS(src, xs + row * DDIM + (lane << 2));
    }
    __syncthreads();    // drains gload_lds + en_lds writes

    // ---- A fragments to registers: 64 rows x 256 dims hi/lo = 128 VGPR ----
    half8 ahf[4][8], alf[4][8];
    const int s7 = l15 & 7;
    #pragma unroll
    for (int n = 0; n < 4; ++n) {
        const float* base = xs + (n * 16 + l15) * DDIM;
        #pragma unroll
        for (int k = 0; k < 8; ++k) {
            int c0 = (k * 8 + l4 * 2) ^ s7;
            float4 f0 = *(const float4*)(base + c0 * 4);
            float4 f1 = *(const float4*)(base + (c0 ^ 1) * 4);
            float ff[8] = {f0.x, f0.y, f0.z, f0.w, f1.x, f1.y, f1.z, f1.w};
            half8 hv, lv;
            #pragma unroll
            for (int j = 0; j < 8; ++j) {
                float v = ff[j];
                _Float16 h = (_Float16)v;
                hv[j] = h; lv[j] = (_Float16)(v - (float)h);
            }
            ahf[n][k] = hv; alf[n][k] = lv;
        }
    }

    // ---- barrier-free main loop: wave w owns codes [w*512, (w+1)*512) ----
    float bestv[4], best2v[4];
    int bidv[4];
    #pragma unroll
    for (int i = 0; i < 4; ++i) { bestv[i] = FLT_BIG; best2v[i] = FLT_BIG; bidv[i] = 0; }

#define TRI(accr, bh_, bl_, ah_, al_) do {                                              \
        accr = __builtin_amdgcn_mfma_f32_16x16x32_f16(bh_, ah_, accr, 0, 0, 0);         \
        accr = __builtin_amdgcn_mfma_f32_16x16x32_f16(bl_, ah_, accr, 0, 0, 0);         \
        accr = __builtin_amdgcn_mfma_f32_16x16x32_f16(bh_, al_, accr, 0, 0, 0);         \
    } while (0)

#define LOADB(T) do {                                                                   \
        _Pragma("unroll") for (int k_ = 0; k_ < 8; ++k_) {                              \
            T##h[k_] = pb[k_ * 128];                                                    \
            T##l[k_] = pb[k_ * 128 + 64];                                               \
        }                                                                               \
        pb += 1024;                                                                     \
    } while (0)

#define COMPUTE(T, gb_) do {                                                            \
        f32x4 acc[4];                                                                   \
        _Pragma("unroll") for (int n_ = 0; n_ < 4; ++n_)                                \
            acc[n_] = (f32x4){0.f, 0.f, 0.f, 0.f};                                      \
        _Pragma("unroll") for (int k_ = 0; k_ < 8; ++k_)                                \
            _Pragma("unroll") for (int n_ = 0; n_ < 4; ++n_)                            \
                TRI(acc[n_], T##h[k_], T##l[k_], ahf[n_][k_], alf[n_][k_]);             \
        float4 e4 = *(const float4*)(en_lds + (gb_) + l4 * 4);                          \
        _Pragma("unroll") for (int r_ = 0; r_ < 4; ++r_) {                              \
            int code = (gb_) + l4 * 4 + r_;                                             \
            float e = (r_ == 0) ? e4.x : (r_ == 1) ? e4.y : (r_ == 2) ? e4.z : e4.w;    \
            _Pragma("unroll") for (int n_ = 0; n_ < 4; ++n_) {                          \
                float dist = fmaf(-2.f, acc[n_][r_], e);                                \
                if (dist < bestv[n_]) {                                                 \
                    best2v[n_] = bestv[n_]; bestv[n_] = dist; bidv[n_] = code;          \
                } else if (dist < best2v[n_]) best2v[n_] = dist;                        \
            }                                                                           \
        }                                                                               \
    } while (0)

    const half8* pb = cbp + (size_t)w * 32768 + lane;   // 32 groups x 1024 half8
    half8 cbh[8], cbl[8], nbh[8], nbl[8];
    int gbase = w * 512;

    LOADB(cb);                                   // group 0
    #pragma unroll 2
    for (int gi = 0; gi < 32; gi += 2) {
        LOADB(nb);                               // group gi+1 (issued before MFMA burst)
        COMPUTE(cb, gbase);
        if (gi + 2 < 32) LOADB(cb);              // group gi+2
        COMPUTE(nb, gbase + 16);
        gbase += 32;
    }
#undef TRI
#undef LOADB
#undef COMPUTE

    // ---- cross-lane merge (over l4): candidates for row n*16+l15 ----
    #pragma unroll
    for (int n = 0; n < 4; ++n) {
        float d = bestv[n], d2 = best2v[n];
        int ix = bidv[n];
        #pragma unroll
        for (int off = 16; off < 64; off <<= 1) {
            float od = __shfl_xor(d, off, 64);
            float od2 = __shfl_xor(d2, off, 64);
            int oi = __shfl_xor(ix, off, 64);
            if (od < d || (od == d && oi < ix)) { d2 = fminf(d, od2); d = od; ix = oi; }
            else d2 = fminf(d2, od);
        }
        if (l4 == 0) {
            int row = n * 16 + l15;
            red_d[w][row] = d;
            red_d2[w][row] = d2;
            red_i[w][row] = ix;
        }
    }
    __syncthreads();

    // ---- cross-wave merge + bidx write + flag append ----
    if (tid < BM) {
        float d = red_d[0][tid], d2 = red_d2[0][tid];
        int ix = red_i[0][tid];
        #pragma unroll
        for (int q = 1; q < 8; ++q) {
            float od = red_d[q][tid], od2 = red_d2[q][tid];
            int oi = red_i[q][tid];
            if (od < d || (od == d && oi < ix)) { d2 = fminf(d, od2); d = od; ix = oi; }
            else d2 = fminf(d2, od);
        }
        bidx[brow + tid] = ix;
        if (d2 - d < DELTA) {
            int pos = atomicAdd(counter, 1);
            list[pos] = brow + tid;
        }
    }
}

// ---------------- exact fp32 rescan: repairs bidx for flagged rows ----------------
__global__ __launch_bounds__(256)
void rescan_kernel(const float* __restrict__ x, const float* __restrict__ cb,
                   const float* __restrict__ en, const int* __restrict__ list,
                   const int* __restrict__ counter, int* __restrict__ bidx) {
    __shared__ __align__(16) float4 xrow4[64];
    __shared__ float wd[4];
    __shared__ int wi[4];
    const int tid = threadIdx.x;
    const int w = tid >> 6;
    const int lane = tid & 63;
    const int cnt = *counter;

    for (int it = blockIdx.x; it < cnt; it += gridDim.x) {
        const int row = list[it];
        __syncthreads();
        if (tid < 64) xrow4[tid] = ((const float4*)&x[(size_t)row * DDIM])[tid];
        __syncthreads();
        const float4 xv = xrow4[lane];
        float bd = FLT_BIG;
        int bi = 0;
        for (int i = 0; i < KCODES / 4; ++i) {
            int code = i * 4 + w;
            const float4 c4 = ((const float4*)&cb[(size_t)code * DDIM])[lane];
            float s = xv.x * c4.x + xv.y * c4.y + xv.z * c4.z + xv.w * c4.w;
            #pragma unroll
            for (int off = 1; off < 64; off <<= 1) s += __shfl_xor(s, off, 64);
            float dist = fmaf(-2.f, s, en[code]);
            if (dist < bd) { bd = dist; bi = code; }
        }
        if (lane == 0) { wd[w] = bd; wi[w] = bi; }
        __syncthreads();
        if (tid == 0) {
            float d = wd[0]; int ix = wi[0];
            #pragma unroll
            for (int q = 1; q < 4; ++q) {
                if (wd[q] < d || (wd[q] == d && wi[q] < ix)) { d = wd[q]; ix = wi[q]; }
            }
            bidx[row] = ix;
        }
    }
}

// ---------------- gather + loss + indices (all rows, final bidx) ----------------
__global__ __launch_bounds__(256)
void gather_kernel(const float* __restrict__ x, const float* __restrict__ cb,
                   const int* __restrict__ bidx, float* __restrict__ out,
                   float* __restrict__ loss_accum, int N) {
    __shared__ float wsum[4];
    __shared__ int bloc[64];
    const int tid = threadIdx.x;
    const int brow = blockIdx.x * 64;
    const size_t ND = (size_t)N * DDIM;
    if (tid < 64) {
        int ix = bidx[brow + tid];
        bloc[tid] = ix;
        out[ND + 1 + brow + tid] = (float)ix;
    }
    __syncthreads();
    float lsum = 0.f;
    #pragma unroll
    for (int pp = 0; pp < 16; ++pp) {
        int i = tid + pp * 256;       // 0..4095 float4-units
        int row = i >> 6;
        int c4 = (i & 63) << 2;
        int code = bloc[row];
        const float4 q = *reinterpret_cast<const float4*>(&cb[(size_t)code * DDIM + c4]);
        const float4 xv = *reinterpret_cast<const float4*>(&x[(size_t)(brow + row) * DDIM + c4]);
        float d0 = xv.x - q.x, d1 = xv.y - q.y, d2 = xv.z - q.z, d3 = xv.w - q.w;
        lsum += d0 * d0 + d1 * d1 + d2 * d2 + d3 * d3;
        *reinterpret_cast<float4*>(&out[(size_t)(brow + row) * DDIM + c4]) = q;
    }
    #pragma unroll
    for (int off = 32; off > 0; off >>= 1) lsum += __shfl_xor(lsum, off, 64);
    if ((tid & 63) == 0) wsum[tid >> 6] = lsum;
    __syncthreads();
    if (tid == 0) {
        float tot = wsum[0] + wsum[1] + wsum[2] + wsum[3];
        atomicAdd(loss_accum, tot * (0.25f / (float)ND));
    }
}

__global__ void loss_fin_kernel(const float* __restrict__ loss_accum,
                                float* __restrict__ out, size_t off) {
    if (blockIdx.x == 0 && threadIdx.x == 0) out[off] = *loss_accum;
}

extern "C" void kernel_launch(void* const* d_in, const int* in_sizes, int n_in,
                              void* d_out, int out_size, void* d_ws, size_t ws_size,
                              hipStream_t stream) {
    const float* x = (const float*)d_in[0];
    const float* cb = (const float*)d_in[1];
    const int N = in_sizes[0] / DDIM;    // 65536
    const int K = in_sizes[1] / DDIM;    // 4096
    float* out = (float*)d_out;

    half8* cbp = (half8*)d_ws;           // 4 MB fragment-ordered codebook
    char* p = (char*)d_ws + (4 << 20);
    float* en = (float*)p;                  p += (size_t)K * 4;
    int* bidx = (int*)p;                    p += (size_t)N * 4;
    int* list = (int*)p;                    p += (size_t)N * 4;
    int* counter = (int*)p;                 p += 64;
    float* loss_accum = (float*)p;

    hipMemsetAsync(counter, 0, sizeof(int), stream);
    hipMemsetAsync(loss_accum, 0, sizeof(float), stream);
    cvt_cb_kernel<<<(K * 32) / 256, 256, 0, stream>>>(cb, cbp);
    enorm_kernel<<<(K * 64) / 256, 256, 0, stream>>>(cb, en, K);
    vq_mfma_kernel<<<N / BM, 512, 0, stream>>>(x, cbp, en, bidx, list, counter);
    rescan_kernel<<<512, 256, 0, stream>>>(x, cb, en, list, counter, bidx);
    gather_kernel<<<N / 64, 256, 0, stream>>>(x, cb, bidx, out, loss_accum, N);
    loss_fin_kernel<<<1, 64, 0, stream>>>(loss_accum, out, (size_t)N * DDIM);
}

// Round 14
// 727.161 us; speedup vs baseline: 3.0185x; 3.0185x over previous
//
#include <hip/hip_runtime.h>
#include <stdint.h>

typedef _Float16 half8 __attribute__((ext_vector_type(8)));
typedef float f32x4 __attribute__((ext_vector_type(4)));

#define DDIM 256
#define KCODES 4096
#define BM 128
#define BN 128
#define DELTA 0.02f
#define FLT_BIG 3.4e38f

#define GLOAD_LDS(gsrc, ldst)                                                        \
    __builtin_amdgcn_global_load_lds(                                                \
        (const __attribute__((address_space(1))) void*)(const void*)(gsrc),          \
        (__attribute__((address_space(3))) void*)(void*)(ldst), 16, 0, 0)

// ---------- fp32 -> hi/lo fp16, layout [row][ch(8)][slot(8)] half8 ----------
// slots per 32-dim chunk: 0-3 = hi quads (dims q*8..q*8+7), 4-7 = lo quads
__global__ void cvt_hl_kernel(const float* __restrict__ src, half8* __restrict__ dst) {
    int gid = blockIdx.x * 256 + threadIdx.x;   // rows*32 threads
    int q = gid & 3;
    int ch = (gid >> 2) & 7;
    long row = gid >> 5;
    const float* s = src + row * DDIM + ch * 32 + q * 8;
    const float4 f0 = ((const float4*)s)[0];
    const float4 f1 = ((const float4*)s)[1];
    float vv[8] = {f0.x, f0.y, f0.z, f0.w, f1.x, f1.y, f1.z, f1.w};
    half8 hi, lo;
    #pragma unroll
    for (int j = 0; j < 8; ++j) {
        float v = vv[j];
        _Float16 h = (_Float16)v;
        hi[j] = h; lo[j] = (_Float16)(v - (float)h);
    }
    half8* d = dst + ((row * 8 + ch) << 3);
    d[q] = hi;
    d[q + 4] = lo;
}

__global__ void enorm_kernel(const float* __restrict__ cb, float* __restrict__ en, int K) {
    int gid = blockIdx.x * blockDim.x + threadIdx.x;
    int code = gid >> 6;
    int lane = threadIdx.x & 63;
    if (code >= K) return;
    const float4 v = *reinterpret_cast<const float4*>(&cb[(size_t)code * DDIM + lane * 4]);
    float s = v.x * v.x + v.y * v.y + v.z * v.z + v.w * v.w;
    #pragma unroll
    for (int off = 32; off > 0; off >>= 1) s += __shfl_xor(s, off, 64);
    if (lane == 0) en[code] = s;
}

// ---------------- main: 128x128 tile, 4 waves, 2 blocks/CU, stage-after-barrier ----------------
__global__ __launch_bounds__(256, 2)
void vq_mfma_kernel(const half8* x16, const half8* __restrict__ cb16,
                    const float* __restrict__ en, int* __restrict__ bidx,
                    int* __restrict__ list, int* __restrict__ counter) {
    __shared__ __align__(16) half8 Abuf[2][BM * 8];   // 2 x 16 KB
    __shared__ __align__(16) half8 Bbuf[2][BN * 8];   // 2 x 16 KB
    __shared__ float red_d[2][BM];
    __shared__ float red_d2[2][BM];
    __shared__ int   red_i[2][BM];

    const int tid = threadIdx.x;
    const int lane = tid & 63;
    const int w = tid >> 6;                  // 4 waves
    const int wr = w >> 1, wc = w & 1;       // 2 x 2, wave-tile 64 rows x 64 codes
    const int l15 = lane & 15, l4 = lane >> 4;
    const int brow = blockIdx.x * BM;

    // ---- persistent stage pointers: 4 A-regions + 4 B-regions per wave ----
    const int lrow = lane >> 3;          // row within 8-row region
    const int swz = (lane & 7) ^ lrow;   // pre-swizzled source slot
    const half8* pA0 = x16 + (size_t)(brow + (w     ) * 8 + lrow) * 64 + swz;
    const half8* pA1 = x16 + (size_t)(brow + (w +  4) * 8 + lrow) * 64 + swz;
    const half8* pA2 = x16 + (size_t)(brow + (w +  8) * 8 + lrow) * 64 + swz;
    const half8* pA3 = x16 + (size_t)(brow + (w + 12) * 8 + lrow) * 64 + swz;
    const half8* pB0 = cb16 + (size_t)((w     ) * 8 + lrow) * 64 + swz;
    const half8* pB1 = cb16 + (size_t)((w +  4) * 8 + lrow) * 64 + swz;
    const half8* pB2 = cb16 + (size_t)((w +  8) * 8 + lrow) * 64 + swz;
    const half8* pB3 = cb16 + (size_t)((w + 12) * 8 + lrow) * 64 + swz;

#define STAGE(b_) do {                                      \
        GLOAD_LDS(pA0, &Abuf[b_][(w     ) * 64]);           \
        GLOAD_LDS(pA1, &Abuf[b_][(w +  4) * 64]);           \
        GLOAD_LDS(pA2, &Abuf[b_][(w +  8) * 64]);           \
        GLOAD_LDS(pA3, &Abuf[b_][(w + 12) * 64]);           \
        GLOAD_LDS(pB0, &Bbuf[b_][(w     ) * 64]);           \
        GLOAD_LDS(pB1, &Bbuf[b_][(w +  4) * 64]);           \
        GLOAD_LDS(pB2, &Bbuf[b_][(w +  8) * 64]);           \
        GLOAD_LDS(pB3, &Bbuf[b_][(w + 12) * 64]);           \
    } while (0)

#define ADVA(dA_, dB_) do {                                 \
        pA0 += dA_; pA1 += dA_; pA2 += dA_; pA3 += dA_;     \
        pB0 += dB_; pB1 += dB_; pB2 += dB_; pB3 += dB_;     \
    } while (0)

    // ---- LDS frag read bases (halfword units) ----
    const int sw7 = l15 & 7;
    const _Float16* A0 = (const _Float16*)Abuf;
    const _Float16* B0 = A0 + 16384;
    const _Float16* aH = A0 + wr * 4096 + l15 * 64 + ((l4    ) ^ sw7) * 8;
    const _Float16* aL = A0 + wr * 4096 + l15 * 64 + ((l4 + 4) ^ sw7) * 8;
    const _Float16* bH = B0 + wc * 4096 + l15 * 64 + ((l4    ) ^ sw7) * 8;
    const _Float16* bL = B0 + wc * 4096 + l15 * 64 + ((l4 + 4) ^ sw7) * 8;

    // prologue: stage (tile0, chunk0) into buf0
    STAGE(0); ADVA(8, 8);

    float bestv[4], best2v[4];
    int bidv[4];
    #pragma unroll
    for (int i = 0; i < 4; ++i) { bestv[i] = FLT_BIG; best2v[i] = FLT_BIG; bidv[i] = 0; }

    const int code_sub = wc * 64 + l4 * 4;
    f32x4 acc[4][4];

#define TRI(accr, bh_, bl_, ah_, al_) do {                                              \
        accr = __builtin_amdgcn_mfma_f32_16x16x32_f16(bh_, ah_, accr, 0, 0, 0);         \
        accr = __builtin_amdgcn_mfma_f32_16x16x32_f16(bl_, ah_, accr, 0, 0, 0);         \
        accr = __builtin_amdgcn_mfma_f32_16x16x32_f16(bh_, al_, accr, 0, 0, 0);         \
    } while (0)

    for (int it = 0; it < 32; ++it) {
        #pragma unroll
        for (int m = 0; m < 4; ++m)
            #pragma unroll
            for (int n = 0; n < 4; ++n) acc[m][n] = (f32x4){0.f, 0.f, 0.f, 0.f};

        #pragma unroll
        for (int k = 0; k < 8; ++k) {
            // drains the stage issued one full step earlier, then publishes
            __syncthreads();
            if (k != 7) {
                STAGE((k + 1) & 1);                  // chunk k+1, same tile
                if (k == 6) ADVA(-56, 8136);         // just staged ch7 -> next tile ch0
                else        ADVA(8, 8);
            } else if (it != 31) {
                STAGE(0);                            // next tile, chunk 0
                ADVA(8, 8);
            }
            __builtin_amdgcn_sched_barrier(0);       // pin stage issue before reads/MFMA

            const int o = (k & 1) ? 8192 : 0;
            half8 ah[4], al[4], bh[4], bl[4];
            #pragma unroll
            for (int i = 0; i < 4; ++i) {
                ah[i] = *(const half8*)(aH + o + i * 1024);
                al[i] = *(const half8*)(aL + o + i * 1024);
                bh[i] = *(const half8*)(bH + o + i * 1024);
                bl[i] = *(const half8*)(bL + o + i * 1024);
            }
            __builtin_amdgcn_s_setprio(1);
            #pragma unroll
            for (int m = 0; m < 4; ++m)
                #pragma unroll
                for (int n = 0; n < 4; ++n)
                    TRI(acc[m][n], bh[m], bl[m], ah[n], al[n]);
            __builtin_amdgcn_s_setprio(0);
        }

        // ---- tile epilogue: dist = ||e||^2 - 2*dot (en from global/L2) ----
        const int c0 = it * BN;
        #pragma unroll
        for (int m = 0; m < 4; ++m) {
            const float4 e4 = *(const float4*)(en + c0 + wc * 64 + m * 16 + l4 * 4);
            #pragma unroll
            for (int r = 0; r < 4; ++r) {
                int code = c0 + code_sub + m * 16 + r;
                float e = (r == 0) ? e4.x : (r == 1) ? e4.y : (r == 2) ? e4.z : e4.w;
                #pragma unroll
                for (int n = 0; n < 4; ++n) {
                    float dist = fmaf(-2.f, acc[m][n][r], e);
                    if (dist < bestv[n]) { best2v[n] = bestv[n]; bestv[n] = dist; bidv[n] = code; }
                    else if (dist < best2v[n]) best2v[n] = dist;
                }
            }
        }
    }
#undef STAGE
#undef ADVA
#undef TRI

    // ---- cross-lane merge: candidates for row (wr*64+n*16+l15) spread over l4 ----
    #pragma unroll
    for (int n = 0; n < 4; ++n) {
        float d = bestv[n], d2 = best2v[n];
        int ix = bidv[n];
        #pragma unroll
        for (int off = 16; off < 64; off <<= 1) {
            float od = __shfl_xor(d, off, 64);
            float od2 = __shfl_xor(d2, off, 64);
            int oi = __shfl_xor(ix, off, 64);
            if (od < d || (od == d && oi < ix)) { d2 = fminf(d, od2); d = od; ix = oi; }
            else d2 = fminf(d2, od);
        }
        if (l4 == 0) {
            int row = wr * 64 + n * 16 + l15;
            red_d[wc][row] = d;
            red_d2[wc][row] = d2;
            red_i[wc][row] = ix;
        }
    }
    __syncthreads();

    // ---- cross-wave merge + bidx write + flag append ----
    if (tid < BM) {
        float d = red_d[0][tid], d2 = red_d2[0][tid];
        int ix = red_i[0][tid];
        float od = red_d[1][tid], od2 = red_d2[1][tid];
        int oi = red_i[1][tid];
        if (od < d || (od == d && oi < ix)) { d2 = fminf(d, od2); d = od; ix = oi; }
        else d2 = fminf(d2, od);
        bidx[brow + tid] = ix;
        if (d2 - d < DELTA) {
            int pos = atomicAdd(counter, 1);
            list[pos] = brow + tid;
        }
    }
}

// ---------------- exact fp32 rescan: repairs bidx for flagged rows ----------------
__global__ __launch_bounds__(256)
void rescan_kernel(const float* __restrict__ x, const float* __restrict__ cb,
                   const float* __restrict__ en, const int* __restrict__ list,
                   const int* __restrict__ counter, int* __restrict__ bidx) {
    __shared__ __align__(16) float4 xrow4[64];
    __shared__ float wd[4];
    __shared__ int wi[4];
    const int tid = threadIdx.x;
    const int w = tid >> 6;
    const int lane = tid & 63;
    const int cnt = *counter;

    for (int it = blockIdx.x; it < cnt; it += gridDim.x) {
        const int row = list[it];
        __syncthreads();
        if (tid < 64) xrow4[tid] = ((const float4*)&x[(size_t)row * DDIM])[tid];
        __syncthreads();
        const float4 xv = xrow4[lane];
        float bd = FLT_BIG;
        int bi = 0;
        for (int i = 0; i < KCODES / 4; ++i) {
            int code = i * 4 + w;
            const float4 c4 = ((const float4*)&cb[(size_t)code * DDIM])[lane];
            float s = xv.x * c4.x + xv.y * c4.y + xv.z * c4.z + xv.w * c4.w;
            #pragma unroll
            for (int off = 1; off < 64; off <<= 1) s += __shfl_xor(s, off, 64);
            float dist = fmaf(-2.f, s, en[code]);
            if (dist < bd) { bd = dist; bi = code; }
        }
        if (lane == 0) { wd[w] = bd; wi[w] = bi; }
        __syncthreads();
        if (tid == 0) {
            float d = wd[0]; int ix = wi[0];
            #pragma unroll
            for (int q = 1; q < 4; ++q) {
                if (wd[q] < d || (wd[q] == d && wi[q] < ix)) { d = wd[q]; ix = wi[q]; }
            }
            bidx[row] = ix;
        }
    }
}

// ---------------- gather + loss + indices (all rows, final bidx) ----------------
__global__ __launch_bounds__(256)
void gather_kernel(const float* __restrict__ x, const float* __restrict__ cb,
                   const int* __restrict__ bidx, float* __restrict__ out,
                   float* __restrict__ loss_accum, int N) {
    __shared__ float wsum[4];
    __shared__ int bloc[64];
    const int tid = threadIdx.x;
    const int brow = blockIdx.x * 64;
    const size_t ND = (size_t)N * DDIM;
    if (tid < 64) {
        int ix = bidx[brow + tid];
        bloc[tid] = ix;
        out[ND + 1 + brow + tid] = (float)ix;
    }
    __syncthreads();
    float lsum = 0.f;
    #pragma unroll
    for (int pp = 0; pp < 16; ++pp) {
        int i = tid + pp * 256;       // 0..4095 float4-units
        int row = i >> 6;
        int c4 = (i & 63) << 2;
        int code = bloc[row];
        const float4 q = *reinterpret_cast<const float4*>(&cb[(size_t)code * DDIM + c4]);
        const float4 xv = *reinterpret_cast<const float4*>(&x[(size_t)(brow + row) * DDIM + c4]);
        float d0 = xv.x - q.x, d1 = xv.y - q.y, d2 = xv.z - q.z, d3 = xv.w - q.w;
        lsum += d0 * d0 + d1 * d1 + d2 * d2 + d3 * d3;
        *reinterpret_cast<float4*>(&out[(size_t)(brow + row) * DDIM + c4]) = q;
    }
    #pragma unroll
    for (int off = 32; off > 0; off >>= 1) lsum += __shfl_xor(lsum, off, 64);
    if ((tid & 63) == 0) wsum[tid >> 6] = lsum;
    __syncthreads();
    if (tid == 0) {
        float tot = wsum[0] + wsum[1] + wsum[2] + wsum[3];
        atomicAdd(loss_accum, tot * (0.25f / (float)ND));
    }
}

__global__ void loss_fin_kernel(const float* __restrict__ loss_accum,
                                float* __restrict__ out, size_t off) {
    if (blockIdx.x == 0 && threadIdx.x == 0) out[off] = *loss_accum;
}

extern "C" void kernel_launch(void* const* d_in, const int* in_sizes, int n_in,
                              void* d_out, int out_size, void* d_ws, size_t ws_size,
                              hipStream_t stream) {
    const float* x = (const float*)d_in[0];
    const float* cb = (const float*)d_in[1];
    const int N = in_sizes[0] / DDIM;    // 65536
    const int K = in_sizes[1] / DDIM;    // 4096
    float* out = (float*)d_out;

    // x16 (64 MB) lives in out[0 .. N*D) — overwritten by gather afterwards
    half8* x16 = (half8*)d_out;

    half8* cb16 = (half8*)d_ws;          // 4 MB hi/lo codebook
    char* p = (char*)d_ws + (4 << 20);
    float* en = (float*)p;                  p += (size_t)K * 4;
    int* bidx = (int*)p;                    p += (size_t)N * 4;
    int* list = (int*)p;                    p += (size_t)N * 4;
    int* counter = (int*)p;                 p += 64;
    float* loss_accum = (float*)p;

    hipMemsetAsync(counter, 0, sizeof(int), stream);
    hipMemsetAsync(loss_accum, 0, sizeof(float), stream);
    cvt_hl_kernel<<<(N * 32) / 256, 256, 0, stream>>>(x, x16);
    cvt_hl_kernel<<<(K * 32) / 256, 256, 0, stream>>>(cb, cb16);
    enorm_kernel<<<(K * 64) / 256, 256, 0, stream>>>(cb, en, K);
    vq_mfma_kernel<<<N / BM, 256, 0, stream>>>(x16, cb16, en, bidx, list, counter);
    rescan_kernel<<<512, 256, 0, stream>>>(x, cb, en, list, counter, bidx);
    gather_kernel<<<N / 64, 256, 0, stream>>>(x, cb, bidx, out, loss_accum, N);
    loss_fin_kernel<<<1, 64, 0, stream>>>(loss_accum, out, (size_t)N * DDIM);
}